// Round 1
// baseline (2453.546 us; speedup 1.0000x reference)
//
#include <hip/hip_runtime.h>

// Shapes: BS=256, C=256, H=W=16, HW=256, conv1: 1024->1024 3x3, conv2: 1024->512 3x3,
// cls: 512->512 1x1 (only diagonal of PSROI needed -> 2 dots/pixel).
//
// Workspace layout (bytes):
//   featT  @ 0          : bf16 [256 b][256 p][1024 ch]  = 134217728   (ch: r1|corr1|r2|corr2)
//   out1T  @ 134217728  : bf16 [256 b][256 p][1024 o]   = 134217728
//   W1b    @ 268435456  : bf16 [9][1024][1024]          = 18874368
//   W2b    @ 287309824  : bf16 [9][512][1024]           = 9437184
//   s1     @ 296747008  : f32  [256*256]                = 262144
//   s2     @ 297009152  : f32  [256*256]                = 262144
//   out2T  @ 0 (overlays featT, dead after conv1): bf16 [256][256][512] = 67108864
// total ~297.3 MB

typedef __attribute__((ext_vector_type(8))) __bf16 bf16x8;
typedef __attribute__((ext_vector_type(4))) float f32x4;
typedef unsigned short u16;

__device__ __forceinline__ u16 f2bf(float f) {
  union { float f; unsigned u; } v; v.f = f;
  unsigned u = v.u;
  u += 0x7fffu + ((u >> 16) & 1u);   // RNE
  return (u16)(u >> 16);
}
__device__ __forceinline__ float bf2f(u16 h) {
  union { unsigned u; float f; } v; v.u = ((unsigned)h) << 16;
  return v.f;
}
__device__ __forceinline__ void gl2lds16(const void* g, void* l) {
  __builtin_amdgcn_global_load_lds(
      (__attribute__((address_space(1))) void*)(void*)g,
      (__attribute__((address_space(3))) void*)l, 16, 0, 0);
}

// ---------------------------------------------------------------------------
// Kernel 1: relu + channel-L2-norm scales + bf16 transpose to featT[b][p][ch]
// grid 1024, block 256. block bx: b = bx>>2, p0 = (bx&3)*64.
// thread t: p = p0 + (t&63), c-range = [(t>>6)*64, +64)
__global__ __launch_bounds__(256) void k_norm(const float* __restrict__ f1,
                                              const float* __restrict__ f2,
                                              u16* __restrict__ featT,
                                              float* __restrict__ s1,
                                              float* __restrict__ s2) {
  int bx = blockIdx.x;
  int b = bx >> 2;
  int p0 = (bx & 3) << 6;
  int t = threadIdx.x;
  int p = p0 + (t & 63);
  int cg = t >> 6;
  const float* F1 = f1 + ((size_t)b << 16);
  const float* F2 = f2 + ((size_t)b << 16);
  u16* FT = featT + (((size_t)(b << 8) + p) << 10);
  float ss1 = 0.f, ss2 = 0.f;
  for (int i = 0; i < 64; ++i) {
    int c = (cg << 6) + i;
    float v1 = F1[(c << 8) + p]; v1 = v1 > 0.f ? v1 : 0.f;
    float v2 = F2[(c << 8) + p]; v2 = v2 > 0.f ? v2 : 0.f;
    ss1 += v1 * v1; ss2 += v2 * v2;
    FT[c] = f2bf(v1);
    FT[512 + c] = f2bf(v2);
  }
  __shared__ float l1[256], l2[256];
  l1[t] = ss1; l2[t] = ss2;
  __syncthreads();
  if (t < 64) {
    float a = l1[t] + l1[t + 64] + l1[t + 128] + l1[t + 192];
    float c2 = l2[t] + l2[t + 64] + l2[t + 128] + l2[t + 192];
    int pp = (b << 8) + p0 + t;
    s1[pp] = 1.f / fmaxf(sqrtf(a), 1e-12f);
    s2[pp] = 1.f / fmaxf(sqrtf(c2), 1e-12f);
  }
}

// ---------------------------------------------------------------------------
// Kernel 2: weight repack fp32 [O][C][3][3] -> bf16 [tap][O][C]
__global__ __launch_bounds__(256) void k_wconv(const float* __restrict__ w,
                                               u16* __restrict__ wb, int OC, int C) {
  int idx = blockIdx.x * 256 + threadIdx.x;
  if (idx >= 9 * OC) return;
  int tap = idx / OC;
  int r = idx - tap * OC;
  int o = r / C;
  int c = r - o * C;
  wb[idx] = f2bf(w[(size_t)(o * C + c) * 9 + tap]);
}

// ---------------------------------------------------------------------------
// Kernel 3: Gram GEMM G[p1][p2] = sum_c r1[p1][c]*r2[p2][c], scaled epilogue.
// grid 1024: b = bx>>2, p1-tile = (bx>>1)&1, p2-tile = bx&1. block 256 = 4 waves 2x2.
__global__ __launch_bounds__(256) void k_corr(u16* featT,
                                              const float* __restrict__ s1,
                                              const float* __restrict__ s2,
                                              float* __restrict__ out) {
  __shared__ alignas(16) u16 Alds[128 * 32];
  __shared__ alignas(16) u16 Blds[128 * 32];
  int bx = blockIdx.x;
  int b = bx >> 2;
  int p1b = ((bx >> 1) & 1) << 7;
  int p2b = (bx & 1) << 7;
  int t = threadIdx.x, l = t & 63, w = t >> 6;
  int wm = w >> 1, wn = w & 1, lr = l & 15, lq = l >> 4;
  int srow = (w << 4) + (l >> 2);
  int sq = (l & 3) << 3;
  const size_t bbase = (size_t)b << 18;

  f32x4 acc[4][4];
#pragma unroll
  for (int i = 0; i < 4; ++i)
#pragma unroll
    for (int j = 0; j < 4; ++j) acc[i][j] = (f32x4){0.f, 0.f, 0.f, 0.f};

#pragma unroll 1
  for (int kc = 0; kc < 8; ++kc) {
    int c0 = kc << 5;
    const u16* sA = featT + bbase + ((size_t)(p1b + srow) << 10) + (c0 + sq);
    gl2lds16(sA, Alds + ((w << 4) << 5));
    gl2lds16(sA + (64 << 10), Alds + ((64 + (w << 4)) << 5));
    const u16* sB = featT + bbase + ((size_t)(p2b + srow) << 10) + (512 + c0 + sq);
    gl2lds16(sB, Blds + ((w << 4) << 5));
    gl2lds16(sB + (64 << 10), Blds + ((64 + (w << 4)) << 5));
    __syncthreads();
    bf16x8 af[4], bfr[4];
#pragma unroll
    for (int mf = 0; mf < 4; ++mf)
      af[mf] = *(const bf16x8*)(Alds + (((wm << 6) + (mf << 4) + lr) << 5) + (lq << 3));
#pragma unroll
    for (int nf = 0; nf < 4; ++nf)
      bfr[nf] = *(const bf16x8*)(Blds + (((wn << 6) + (nf << 4) + lr) << 5) + (lq << 3));
#pragma unroll
    for (int mf = 0; mf < 4; ++mf)
#pragma unroll
      for (int nf = 0; nf < 4; ++nf)
        acc[mf][nf] = __builtin_amdgcn_mfma_f32_16x16x32_bf16(af[mf], bfr[nf], acc[mf][nf], 0, 0, 0);
    __syncthreads();
  }

  float sc2[4]; int p2g[4];
#pragma unroll
  for (int nf = 0; nf < 4; ++nf) {
    int p2 = p2b + (wn << 6) + (nf << 4) + lr;
    p2g[nf] = p2;
    sc2[nf] = s2[(b << 8) + p2];
  }
  float* corr1 = out + 512;
  float* corr2 = out + 512 + 16777216;
#pragma unroll
  for (int mf = 0; mf < 4; ++mf) {
#pragma unroll
    for (int r = 0; r < 4; ++r) {
      int p1 = p1b + (wm << 6) + (mf << 4) + (lq << 2) + r;
      float sc1v = s1[(b << 8) + p1];
#pragma unroll
      for (int nf = 0; nf < 4; ++nf) {
        int p2 = p2g[nf];
        float g = acc[mf][nf][r] * sc1v * sc2[nf];
        // corr1[b][k=p2][p=p1] = G[p1][p2]; corr2[b][k=p1][p=p2] = G[p1][p2]
        corr2[((size_t)b << 16) + ((size_t)p1 << 8) + p2] = g;
        corr1[((size_t)b << 16) + ((size_t)p2 << 8) + p1] = g;
        featT[bbase + ((size_t)p1 << 10) + 256 + p2] = f2bf(g);
        featT[bbase + ((size_t)p2 << 10) + 768 + p1] = f2bf(g);
      }
    }
  }
}

// ---------------------------------------------------------------------------
// Kernel 4/5: implicit-GEMM 3x3 conv, D[p][o] = sum_{c,tap} X[p'(p,tap)][c]*W[tap][o][c].
// M = p (A-side, border-masked), N = o (B-side = weights). Tile 128x128, BK=32, 9-tap loop.
// grid: (O/128) * 2 * 256; otile = bx & mask so each o-slice pins to one XCD's L2.
__global__ __launch_bounds__(256) void k_conv(const u16* __restrict__ X,
                                              const u16* __restrict__ Wb,
                                              const float* __restrict__ bias,
                                              u16* __restrict__ Out, int O, int otbits) {
  __shared__ alignas(16) u16 Xlds[256 * 32];
  __shared__ alignas(16) u16 Wlds[128 * 32];
  int bx = blockIdx.x;
  int otile = bx & ((1 << otbits) - 1);
  int rest = bx >> otbits;
  int ptile = rest & 1;
  int b = rest >> 1;
  int t = threadIdx.x, l = t & 63, w = t >> 6;
  int wm = w >> 1, wn = w & 1, lr = l & 15, lq = l >> 4;
  int o0 = otile << 7, p0 = ptile << 7;
  int srow = (w << 4) + (l >> 2);
  int sq = (l & 3) << 3;
  const size_t xbase = (size_t)b << 18;

  int pabs[4], rimg[4], cimg[4];
#pragma unroll
  for (int mf = 0; mf < 4; ++mf) {
    int p = p0 + (wm << 6) + (mf << 4) + lr;
    pabs[mf] = p; rimg[mf] = p >> 4; cimg[mf] = p & 15;
  }
  f32x4 acc[4][4];
#pragma unroll
  for (int i = 0; i < 4; ++i)
#pragma unroll
    for (int j = 0; j < 4; ++j) acc[i][j] = (f32x4){0.f, 0.f, 0.f, 0.f};

  bf16x8 zv;
#pragma unroll
  for (int i = 0; i < 8; ++i) zv[i] = (__bf16)0.f;

#pragma unroll 1
  for (int kc = 0; kc < 32; ++kc) {
    int c0 = kc << 5;
#pragma unroll
    for (int j = 0; j < 4; ++j) {  // stage whole image's 256 rows x 32 ch
      const u16* s = X + xbase + ((size_t)((j << 6) + srow) << 10) + (c0 + sq);
      gl2lds16(s, Xlds + (((j << 6) + (w << 4)) << 5));
    }
#pragma unroll 1
    for (int tap = 0; tap < 9; ++tap) {
      const u16* sW = Wb + (((size_t)tap * O + o0 + srow) << 10) + (c0 + sq);
      gl2lds16(sW, Wlds + ((w << 4) << 5));
      gl2lds16(sW + (64 << 10), Wlds + ((64 + (w << 4)) << 5));
      __syncthreads();
      int kh = tap / 3;
      int dr = kh - 1, dc = tap - kh * 3 - 1;
      int dp = (dr << 4) + dc;
      bf16x8 bwf[4];
#pragma unroll
      for (int nf = 0; nf < 4; ++nf)
        bwf[nf] = *(const bf16x8*)(Wlds + (((wn << 6) + (nf << 4) + lr) << 5) + (lq << 3));
      bf16x8 axf[4];
#pragma unroll
      for (int mf = 0; mf < 4; ++mf) {
        int rr = rimg[mf] + dr, cc = cimg[mf] + dc;
        bool valid = ((unsigned)rr < 16u) && ((unsigned)cc < 16u);
        int pread = valid ? pabs[mf] + dp : 0;
        bf16x8 v = *(const bf16x8*)(Xlds + ((size_t)pread << 5) + (lq << 3));
        axf[mf] = valid ? v : zv;
      }
#pragma unroll
      for (int mf = 0; mf < 4; ++mf)
#pragma unroll
        for (int nf = 0; nf < 4; ++nf)
          acc[mf][nf] = __builtin_amdgcn_mfma_f32_16x16x32_bf16(axf[mf], bwf[nf], acc[mf][nf], 0, 0, 0);
      __syncthreads();
    }
  }

  float bv[4]; int og[4];
#pragma unroll
  for (int nf = 0; nf < 4; ++nf) {
    int o = o0 + (wn << 6) + (nf << 4) + lr;
    og[nf] = o; bv[nf] = bias[o];
  }
#pragma unroll
  for (int mf = 0; mf < 4; ++mf)
#pragma unroll
    for (int r = 0; r < 4; ++r) {
      int p = p0 + (wm << 6) + (mf << 4) + (lq << 2) + r;
      size_t rb = (size_t)((b << 8) + p) * O;
#pragma unroll
      for (int nf = 0; nf < 4; ++nf) {
        float vv = acc[mf][nf][r] + bv[nf];
        Out[rb + og[nf]] = f2bf(vv > 0.f ? vv : 0.f);
      }
    }
}

// ---------------------------------------------------------------------------
// Kernel 6: cls head. Only diagonal PSROI channels survive:
// score[b][c] = mean_p relu( sum_ch out2T[b][p][ch] * Wc[c*256+p][ch] ), softmax over c.
__global__ __launch_bounds__(256) void k_cls(const u16* __restrict__ X2,
                                             const float* __restrict__ Wc,
                                             float* __restrict__ out) {
  int b = blockIdx.x, p = threadIdx.x;
  const uint4* xv = (const uint4*)(X2 + (((size_t)(b << 8) + p) << 9));
  const float4* w0 = (const float4*)(Wc + ((size_t)p << 9));
  const float4* w1 = (const float4*)(Wc + ((size_t)(256 + p) << 9));
  float a0 = 0.f, a1 = 0.f;
#pragma unroll 4
  for (int i = 0; i < 64; ++i) {
    uint4 u = xv[i];
    float x0 = bf2f((u16)(u.x & 0xffffu)), x1 = bf2f((u16)(u.x >> 16));
    float x2 = bf2f((u16)(u.y & 0xffffu)), x3 = bf2f((u16)(u.y >> 16));
    float x4 = bf2f((u16)(u.z & 0xffffu)), x5 = bf2f((u16)(u.z >> 16));
    float x6 = bf2f((u16)(u.w & 0xffffu)), x7 = bf2f((u16)(u.w >> 16));
    float4 wa = w0[i * 2], wb = w0[i * 2 + 1];
    a0 += x0 * wa.x + x1 * wa.y + x2 * wa.z + x3 * wa.w +
          x4 * wb.x + x5 * wb.y + x6 * wb.z + x7 * wb.w;
    float4 wc4 = w1[i * 2], wd = w1[i * 2 + 1];
    a1 += x0 * wc4.x + x1 * wc4.y + x2 * wc4.z + x3 * wc4.w +
          x4 * wd.x + x5 * wd.y + x6 * wd.z + x7 * wd.w;
  }
  a0 = fmaxf(a0, 0.f);
  a1 = fmaxf(a1, 0.f);
  __shared__ float r0[256], r1[256];
  r0[p] = a0; r1[p] = a1;
  for (int s = 128; s > 0; s >>= 1) {
    __syncthreads();
    if (p < s) { r0[p] += r0[p + s]; r1[p] += r1[p + s]; }
  }
  __syncthreads();
  if (p == 0) {
    float s0 = r0[0] * (1.f / 256.f), s1v = r1[0] * (1.f / 256.f);
    float m = fmaxf(s0, s1v);
    float e0 = expf(s0 - m), e1 = expf(s1v - m);
    float inv = 1.f / (e0 + e1);
    out[(b << 1) + 0] = e0 * inv;
    out[(b << 1) + 1] = e1 * inv;
  }
}

// ---------------------------------------------------------------------------
extern "C" void kernel_launch(void* const* d_in, const int* in_sizes, int n_in,
                              void* d_out, int out_size, void* d_ws, size_t ws_size,
                              hipStream_t stream) {
  const float* f1 = (const float*)d_in[0];
  const float* f2 = (const float*)d_in[1];
  const float* w1 = (const float*)d_in[2];
  const float* b1 = (const float*)d_in[3];
  const float* w2 = (const float*)d_in[4];
  const float* b2 = (const float*)d_in[5];
  const float* wc = (const float*)d_in[6];
  float* out = (float*)d_out;
  char* ws = (char*)d_ws;

  u16* featT = (u16*)(ws + 0);
  u16* out1T = (u16*)(ws + 134217728);
  u16* W1b   = (u16*)(ws + 268435456);
  u16* W2b   = (u16*)(ws + 287309824);
  float* s1  = (float*)(ws + 296747008);
  float* s2  = (float*)(ws + 297009152);
  u16* out2T = (u16*)(ws + 0);  // overlays featT (dead after conv1)

  k_norm<<<1024, 256, 0, stream>>>(f1, f2, featT, s1, s2);
  k_wconv<<<(9 * 1024 * 1024 + 255) / 256, 256, 0, stream>>>(w1, W1b, 1024 * 1024, 1024);
  k_wconv<<<(9 * 512 * 1024 + 255) / 256, 256, 0, stream>>>(w2, W2b, 512 * 1024, 1024);
  k_corr<<<1024, 256, 0, stream>>>(featT, s1, s2, out);
  k_conv<<<4096, 256, 0, stream>>>(featT, W1b, b1, out1T, 1024, 3);
  k_conv<<<2048, 256, 0, stream>>>(out1T, W2b, b2, out2T, 512, 2);
  k_cls<<<256, 256, 0, stream>>>(out2T, wc, out);
}

// Round 2
// 1831.608 us; speedup vs baseline: 1.3396x; 1.3396x over previous
//
#include <hip/hip_runtime.h>

// Shapes: BS=256, C=256, H=W=16, HW=256, conv1: 1024->1024 3x3, conv2: 1024->512 3x3,
// cls: 512->512 1x1 (only diagonal of PSROI needed -> 2 dots/pixel).
//
// Workspace layout (bytes):
//   featT  @ 0          : bf16 [256 b][256 p][1024 ch]  = 134217728   (ch: r1|corr1|r2|corr2)
//   out1T  @ 134217728  : bf16 [256 b][256 p][1024 o]   = 134217728
//   W1b    @ 268435456  : bf16 [9][1024][1024]          = 18874368
//   W2b    @ 287309824  : bf16 [9][512][1024]           = 9437184
//   s1     @ 296747008  : f32  [256*256]                = 262144
//   s2     @ 297009152  : f32  [256*256]                = 262144
//   out2T  @ 0 (overlays featT, dead after conv1): bf16 [256][256][512] = 67108864

typedef __attribute__((ext_vector_type(8))) __bf16 bf16x8;
typedef __attribute__((ext_vector_type(4))) float f32x4;
typedef unsigned short u16;

template <bool B> struct BC { static constexpr bool value = B; };

__device__ __forceinline__ u16 f2bf(float f) {
  union { float f; unsigned u; } v; v.f = f;
  unsigned u = v.u;
  u += 0x7fffu + ((u >> 16) & 1u);   // RNE
  return (u16)(u >> 16);
}
__device__ __forceinline__ float bf2f(u16 h) {
  union { unsigned u; float f; } v; v.u = ((unsigned)h) << 16;
  return v.f;
}
__device__ __forceinline__ void gl2lds16(const void* g, void* l) {
  __builtin_amdgcn_global_load_lds(
      (__attribute__((address_space(1))) void*)(void*)g,
      (__attribute__((address_space(3))) void*)l, 16, 0, 0);
}

// ---------------------------------------------------------------------------
// Kernel 1: relu + channel-L2-norm scales + bf16 transpose to featT[b][p][ch]
__global__ __launch_bounds__(256) void k_norm(const float* __restrict__ f1,
                                              const float* __restrict__ f2,
                                              u16* __restrict__ featT,
                                              float* __restrict__ s1,
                                              float* __restrict__ s2) {
  int bx = blockIdx.x;
  int b = bx >> 2;
  int p0 = (bx & 3) << 6;
  int t = threadIdx.x;
  int p = p0 + (t & 63);
  int cg = t >> 6;
  const float* F1 = f1 + ((size_t)b << 16);
  const float* F2 = f2 + ((size_t)b << 16);
  u16* FT = featT + (((size_t)(b << 8) + p) << 10);
  float ss1 = 0.f, ss2 = 0.f;
  for (int i = 0; i < 64; ++i) {
    int c = (cg << 6) + i;
    float v1 = F1[(c << 8) + p]; v1 = v1 > 0.f ? v1 : 0.f;
    float v2 = F2[(c << 8) + p]; v2 = v2 > 0.f ? v2 : 0.f;
    ss1 += v1 * v1; ss2 += v2 * v2;
    FT[c] = f2bf(v1);
    FT[512 + c] = f2bf(v2);
  }
  __shared__ float l1[256], l2[256];
  l1[t] = ss1; l2[t] = ss2;
  __syncthreads();
  if (t < 64) {
    float a = l1[t] + l1[t + 64] + l1[t + 128] + l1[t + 192];
    float c2 = l2[t] + l2[t + 64] + l2[t + 128] + l2[t + 192];
    int pp = (b << 8) + p0 + t;
    s1[pp] = 1.f / fmaxf(sqrtf(a), 1e-12f);
    s2[pp] = 1.f / fmaxf(sqrtf(c2), 1e-12f);
  }
}

// ---------------------------------------------------------------------------
// Kernel 2: weight repack fp32 [O][C][3][3] -> bf16 [tap][O][C].
// One block per o: contiguous reads, coalesced per-tap writes.
__global__ __launch_bounds__(256) void k_wconv(const float* __restrict__ w,
                                               u16* __restrict__ wb, int O, int C) {
  int o = blockIdx.x;
  int t = threadIdx.x;
  const float* src = w + (size_t)o * C * 9;
  for (int c = t; c < C; c += 256) {
    const float* s = src + c * 9;
    float v[9];
#pragma unroll
    for (int i = 0; i < 9; ++i) v[i] = s[i];
#pragma unroll
    for (int tap = 0; tap < 9; ++tap)
      wb[(size_t)tap * O * C + (size_t)o * C + c] = f2bf(v[tap]);
  }
}

// ---------------------------------------------------------------------------
// Kernel 3: Gram GEMM G[p1][p2] = sum_c r1[p1][c]*r2[p2][c], scaled epilogue.
// grid 1024: b = bx>>2, p1-tile = (bx>>1)&1, p2-tile = bx&1. block 256 = 4 waves 2x2.
__global__ __launch_bounds__(256) void k_corr(u16* featT,
                                              const float* __restrict__ s1,
                                              const float* __restrict__ s2,
                                              float* __restrict__ out) {
  __shared__ alignas(16) u16 Alds[128 * 32];
  __shared__ alignas(16) u16 Blds[128 * 32];
  __shared__ float tb[4][16][66];
  int bx = blockIdx.x;
  int b = bx >> 2;
  int p1b = ((bx >> 1) & 1) << 7;
  int p2b = (bx & 1) << 7;
  int t = threadIdx.x, l = t & 63, w = t >> 6;
  int wm = w >> 1, wn = w & 1, lr = l & 15, lq = l >> 4;
  int srow = (w << 4) + (l >> 2);
  int sq = (l & 3) << 3;
  const size_t bbase = (size_t)b << 18;

  f32x4 acc[4][4];
#pragma unroll
  for (int i = 0; i < 4; ++i)
#pragma unroll
    for (int j = 0; j < 4; ++j) acc[i][j] = (f32x4){0.f, 0.f, 0.f, 0.f};

#pragma unroll 1
  for (int kc = 0; kc < 8; ++kc) {
    int c0 = kc << 5;
    const u16* sA = featT + bbase + ((size_t)(p1b + srow) << 10) + (c0 + sq);
    gl2lds16(sA, Alds + ((w << 4) << 5));
    gl2lds16(sA + (64 << 10), Alds + ((64 + (w << 4)) << 5));
    const u16* sB = featT + bbase + ((size_t)(p2b + srow) << 10) + (512 + c0 + sq);
    gl2lds16(sB, Blds + ((w << 4) << 5));
    gl2lds16(sB + (64 << 10), Blds + ((64 + (w << 4)) << 5));
    __syncthreads();
    bf16x8 af[4], bfr[4];
#pragma unroll
    for (int mf = 0; mf < 4; ++mf)
      af[mf] = *(const bf16x8*)(Alds + (((wm << 6) + (mf << 4) + lr) << 5) + (lq << 3));
#pragma unroll
    for (int nf = 0; nf < 4; ++nf)
      bfr[nf] = *(const bf16x8*)(Blds + (((wn << 6) + (nf << 4) + lr) << 5) + (lq << 3));
#pragma unroll
    for (int mf = 0; mf < 4; ++mf)
#pragma unroll
      for (int nf = 0; nf < 4; ++nf)
        acc[mf][nf] = __builtin_amdgcn_mfma_f32_16x16x32_bf16(af[mf], bfr[nf], acc[mf][nf], 0, 0, 0);
    __syncthreads();
  }

  float sc2[4]; int p2g[4];
#pragma unroll
  for (int nf = 0; nf < 4; ++nf) {
    int p2 = p2b + (wn << 6) + (nf << 4) + lr;
    p2g[nf] = p2;
    sc2[nf] = s2[(b << 8) + p2];
  }
  float* corr1 = out + 512;
  float* corr2 = out + 512 + 16777216;
#pragma unroll
  for (int mf = 0; mf < 4; ++mf) {
    float gv[4][4];
#pragma unroll
    for (int r = 0; r < 4; ++r) {
      int p1 = p1b + (wm << 6) + (mf << 4) + (lq << 2) + r;
      float s1v = s1[(b << 8) + p1];
#pragma unroll
      for (int nf = 0; nf < 4; ++nf) gv[nf][r] = acc[mf][nf][r] * s1v * sc2[nf];
    }
    // direct-layout writes: corr2[p1][p2] f32 (64B segs), featT[p1][256+p2] bf16 (32B segs)
#pragma unroll
    for (int r = 0; r < 4; ++r) {
      int p1 = p1b + (wm << 6) + (mf << 4) + (lq << 2) + r;
#pragma unroll
      for (int nf = 0; nf < 4; ++nf) {
        corr2[((size_t)b << 16) + ((size_t)p1 << 8) + p2g[nf]] = gv[nf][r];
        featT[bbase + ((size_t)p1 << 10) + 256 + p2g[nf]] = f2bf(gv[nf][r]);
      }
    }
    // transposed writes via LDS: corr1[p2][p1] f32 (64B segs), featT[p2][768+p1] bf16
#pragma unroll
    for (int r = 0; r < 4; ++r)
#pragma unroll
      for (int nf = 0; nf < 4; ++nf)
        tb[w][(lq << 2) + r][(nf << 4) + lr] = gv[nf][r];
#pragma unroll
    for (int j = 0; j < 16; ++j) {
      float v = tb[w][lr][(j << 2) + lq];
      int p2 = p2b + (wn << 6) + (j << 2) + lq;
      int p1 = p1b + (wm << 6) + (mf << 4) + lr;
      corr1[((size_t)b << 16) + ((size_t)p2 << 8) + p1] = v;
      featT[bbase + ((size_t)p2 << 10) + 768 + p1] = f2bf(v);
    }
  }
}

// ---------------------------------------------------------------------------
// Kernel 4/5: implicit-GEMM 3x3 conv, D[p][o] = sum_{c,tap} X[p'(p,tap)][c]*W[tap][o][c].
// Block = whole image M=256 x N=128 o, 512 threads = 8 waves (4 M x 2 N) of 64x64 tiles.
// K-pipeline: one barrier per (kc,tap) step; stages issued AFTER the barrier into
// double-buffered W (8 KB) / X (16 KB) so the barrier's vmcnt(0) only drains loads
// issued a full compute-period earlier. Border masking via zero-row redirect.
template <int O, int OTB>
__global__ __launch_bounds__(512, 4) void k_conv(const u16* __restrict__ X,
                                                 const u16* __restrict__ Wb,
                                                 const float* __restrict__ bias,
                                                 u16* __restrict__ Out) {
  __shared__ alignas(16) u16 Xlds[2][260 * 32];  // rows 0..255 data, row 256 = zeros
  __shared__ alignas(16) u16 Wlds[2][128 * 32];
  int bx = blockIdx.x;
  int otile = bx & ((1 << OTB) - 1);   // low bits -> XCD affinity for the W slice
  int b = bx >> OTB;
  int t = threadIdx.x, l = t & 63, w = t >> 6;
  int wm = w & 3, wn = w >> 2;
  int lr = l & 15, lq = l >> 4;
  int o0 = otile << 7;
  int srl = l >> 2;
  int sq = (l & 3) << 3;
  const size_t xbase = (size_t)b << 18;

  const u16* wsrc = Wb + (((size_t)(o0 + (w << 4) + srl)) << 10) + sq;
  const u16* xsrc0 = X + xbase + (((size_t)((w << 4) + srl)) << 10) + sq;
  const u16* xsrc1 = xsrc0 + ((size_t)128 << 10);

  u16* wdst0 = &Wlds[0][(w << 4) << 5];
  u16* wdst1 = &Wlds[1][(w << 4) << 5];
  u16* xdA0 = &Xlds[0][(w << 4) << 5];
  u16* xdA1 = &Xlds[0][(128 + (w << 4)) << 5];
  u16* xdB0 = &Xlds[1][(w << 4) << 5];
  u16* xdB1 = &Xlds[1][(128 + (w << 4)) << 5];

  const u16* bwb0 = &Wlds[0][(((wn << 6) + lr) << 5) + (lq << 3)];
  const u16* bwb1 = &Wlds[1][(((wn << 6) + lr) << 5) + (lq << 3)];

  int pb[4];
#pragma unroll
  for (int mf = 0; mf < 4; ++mf)
    pb[mf] = (((wm << 6) + (mf << 4) + lr) << 5) + (lq << 3);
  const int zoff = (256 << 5) + (lq << 3);

  f32x4 acc[4][4];
#pragma unroll
  for (int i = 0; i < 4; ++i)
#pragma unroll
    for (int j = 0; j < 4; ++j) acc[i][j] = (f32x4){0.f, 0.f, 0.f, 0.f};

  if (t < 32) ((unsigned*)&Xlds[t >> 4][256 << 5])[t & 15] = 0u;

  // prologue: stage X(kc=0) -> buf0, W(kc=0,tap=0) -> buf0
  gl2lds16(xsrc0, xdA0);
  gl2lds16(xsrc1, xdA1);
  gl2lds16(wsrc, wdst0);

  auto kcbody = [&](auto oddc, int kc) {
    constexpr bool ODD = decltype(oddc)::value;
    const u16* xb = ODD ? &Xlds[1][0] : &Xlds[0][0];
#pragma unroll
    for (int tap = 0; tap < 9; ++tap) {
      __syncthreads();
      // stage W for step s+1 into buf[(s+1)&1]; s parity = (kc+tap)&1
      int ntap = (tap == 8) ? 0 : tap + 1;
      int nkc = (tap == 8) ? kc + 1 : kc;   // harmless OOB garbage at very end (in-ws)
      bool np1 = ((ODD ? 1 : 0) ^ (tap & 1)) == 0;
      gl2lds16(wsrc + (size_t)ntap * ((size_t)O << 10) + (nkc << 5), np1 ? wdst1 : wdst0);
      if (tap == 0) {  // stage X(kc+1) into the other X buffer (needed 9 steps later)
        if (ODD) { gl2lds16(xsrc0 + ((kc + 1) << 5), xdA0); gl2lds16(xsrc1 + ((kc + 1) << 5), xdA1); }
        else     { gl2lds16(xsrc0 + ((kc + 1) << 5), xdB0); gl2lds16(xsrc1 + ((kc + 1) << 5), xdB1); }
      }
      const u16* bwb = (((ODD ? 1 : 0) ^ (tap & 1)) == 1) ? bwb1 : bwb0;
      bf16x8 bwf[4];
#pragma unroll
      for (int nf = 0; nf < 4; ++nf) bwf[nf] = *(const bf16x8*)(bwb + (nf << 9));
      const int dr = tap / 3 - 1, dc = tap % 3 - 1;
      const int dpo = ((dr << 4) + dc) << 5;
      bf16x8 axf[4];
#pragma unroll
      for (int mf = 0; mf < 4; ++mf) {
        int rr = (wm << 2) + mf + dr;
        bool v = ((unsigned)rr < 16u) & ((unsigned)(lr + dc) < 16u);
        int off = v ? (pb[mf] + dpo) : zoff;
        axf[mf] = *(const bf16x8*)(xb + off);
      }
#pragma unroll
      for (int mf = 0; mf < 4; ++mf)
#pragma unroll
        for (int nf = 0; nf < 4; ++nf)
          acc[mf][nf] = __builtin_amdgcn_mfma_f32_16x16x32_bf16(axf[mf], bwf[nf], acc[mf][nf], 0, 0, 0);
    }
  };

#pragma unroll 1
  for (int kc2 = 0; kc2 < 16; ++kc2) {
    kcbody(BC<false>{}, 2 * kc2);
    kcbody(BC<true>{}, 2 * kc2 + 1);
  }

  float bv[4]; int og[4];
#pragma unroll
  for (int nf = 0; nf < 4; ++nf) {
    og[nf] = o0 + (wn << 6) + (nf << 4) + lr;
    bv[nf] = bias[og[nf]];
  }
#pragma unroll
  for (int mf = 0; mf < 4; ++mf)
#pragma unroll
    for (int r = 0; r < 4; ++r) {
      int p = (wm << 6) + (mf << 4) + (lq << 2) + r;
      size_t rb = (size_t)((b << 8) + p) * O;
#pragma unroll
      for (int nf = 0; nf < 4; ++nf) {
        float vv = acc[mf][nf][r] + bv[nf];
        Out[rb + og[nf]] = f2bf(vv > 0.f ? vv : 0.f);
      }
    }
}

// ---------------------------------------------------------------------------
// Kernel 6: cls head. Only diagonal PSROI channels survive:
// score[b][c] = mean_p relu( sum_ch out2T[b][p][ch] * Wc[c*256+p][ch] ), softmax over c.
__global__ __launch_bounds__(256) void k_cls(const u16* __restrict__ X2,
                                             const float* __restrict__ Wc,
                                             float* __restrict__ out) {
  int b = blockIdx.x, p = threadIdx.x;
  const uint4* xv = (const uint4*)(X2 + (((size_t)(b << 8) + p) << 9));
  const float4* w0 = (const float4*)(Wc + ((size_t)p << 9));
  const float4* w1 = (const float4*)(Wc + ((size_t)(256 + p) << 9));
  float a0 = 0.f, a1 = 0.f;
#pragma unroll 4
  for (int i = 0; i < 64; ++i) {
    uint4 u = xv[i];
    float x0 = bf2f((u16)(u.x & 0xffffu)), x1 = bf2f((u16)(u.x >> 16));
    float x2 = bf2f((u16)(u.y & 0xffffu)), x3 = bf2f((u16)(u.y >> 16));
    float x4 = bf2f((u16)(u.z & 0xffffu)), x5 = bf2f((u16)(u.z >> 16));
    float x6 = bf2f((u16)(u.w & 0xffffu)), x7 = bf2f((u16)(u.w >> 16));
    float4 wa = w0[i * 2], wb = w0[i * 2 + 1];
    a0 += x0 * wa.x + x1 * wa.y + x2 * wa.z + x3 * wa.w +
          x4 * wb.x + x5 * wb.y + x6 * wb.z + x7 * wb.w;
    float4 wc4 = w1[i * 2], wd = w1[i * 2 + 1];
    a1 += x0 * wc4.x + x1 * wc4.y + x2 * wc4.z + x3 * wc4.w +
          x4 * wd.x + x5 * wd.y + x6 * wd.z + x7 * wd.w;
  }
  a0 = fmaxf(a0, 0.f);
  a1 = fmaxf(a1, 0.f);
  __shared__ float r0[256], r1[256];
  r0[p] = a0; r1[p] = a1;
  for (int s = 128; s > 0; s >>= 1) {
    __syncthreads();
    if (p < s) { r0[p] += r0[p + s]; r1[p] += r1[p + s]; }
  }
  __syncthreads();
  if (p == 0) {
    float s0 = r0[0] * (1.f / 256.f), s1v = r1[0] * (1.f / 256.f);
    float m = fmaxf(s0, s1v);
    float e0 = expf(s0 - m), e1 = expf(s1v - m);
    float inv = 1.f / (e0 + e1);
    out[(b << 1) + 0] = e0 * inv;
    out[(b << 1) + 1] = e1 * inv;
  }
}

// ---------------------------------------------------------------------------
extern "C" void kernel_launch(void* const* d_in, const int* in_sizes, int n_in,
                              void* d_out, int out_size, void* d_ws, size_t ws_size,
                              hipStream_t stream) {
  const float* f1 = (const float*)d_in[0];
  const float* f2 = (const float*)d_in[1];
  const float* w1 = (const float*)d_in[2];
  const float* b1 = (const float*)d_in[3];
  const float* w2 = (const float*)d_in[4];
  const float* b2 = (const float*)d_in[5];
  const float* wc = (const float*)d_in[6];
  float* out = (float*)d_out;
  char* ws = (char*)d_ws;

  u16* featT = (u16*)(ws + 0);
  u16* out1T = (u16*)(ws + 134217728);
  u16* W1b   = (u16*)(ws + 268435456);
  u16* W2b   = (u16*)(ws + 287309824);
  float* s1  = (float*)(ws + 296747008);
  float* s2  = (float*)(ws + 297009152);
  u16* out2T = (u16*)(ws + 0);  // overlays featT (dead after conv1)

  k_norm<<<1024, 256, 0, stream>>>(f1, f2, featT, s1, s2);
  k_wconv<<<1024, 256, 0, stream>>>(w1, W1b, 1024, 1024);
  k_wconv<<<512, 256, 0, stream>>>(w2, W2b, 512, 1024);
  k_corr<<<1024, 256, 0, stream>>>(featT, s1, s2, out);
  k_conv<1024, 3><<<2048, 512, 0, stream>>>(featT, W1b, b1, out1T);
  k_conv<512, 2><<<1024, 512, 0, stream>>>(out1T, W2b, b2, out2T);
  k_cls<<<256, 256, 0, stream>>>(out2T, wc, out);
}